// Round 3
// baseline (133.237 us; speedup 1.0000x reference)
//
#include <hip/hip_runtime.h>
#include <stdint.h>

// out = tokens @ W_eff + b_eff, where W_eff folds the BULK_DIM=10 depth
// dimension with closed-form weights w_k = (1/10) * sum_{z=k..10} 1/z.
//
// v4: back to the 3-pass structure (prep folds W AND converts tokens->bf16;
// reg-staging A in the GEMM is unwinnable vs the compiler's IR-level load
// sinking -- v2/v3 both landed at VGPR=88 / 58us). The GEMM is rebuilt as a
// BK=32, 4-slot ring, 2-deep-prefetch pipeline with COUNTED vmcnt (never
// drains to 0 in the main loop) + raw s_barrier, per the m218/8-phase
// mechanism: the old __syncthreads() drain exposed full HBM latency of the
// just-issued prefetch every K-iter (both round-0 and v2/v3 were ~45-58us,
// ~380 TF, with everything <13% busy).

static constexpr float FW[10] = {
    0.2928968253968254f, 0.1928968253968254f, 0.1428968253968254f,
    0.1095634920634921f, 0.0845634920634921f, 0.0645634920634921f,
    0.0478968253968254f, 0.0336111111111111f, 0.0211111111111111f,
    0.0100000000000000f};

typedef __attribute__((ext_vector_type(8))) short short8;     // 8 bf16 = 4 VGPR
typedef __attribute__((ext_vector_type(4))) float floatx4;    // 16x16 C/D frag
typedef __attribute__((ext_vector_type(16))) float floatx16;  // 32x32 C/D frag

// round-to-nearest fp32->bf16, pack two into one uint via v_perm_b32
__device__ inline unsigned int bf16pack2(float hi, float lo) {
    unsigned int uh = __float_as_uint(hi) + 0x8000u;
    unsigned int ul = __float_as_uint(lo) + 0x8000u;
    return __builtin_amdgcn_perm(uh, ul, 0x07060302u);  // {hi[31:16], lo[31:16]}
}

#define LDS_AS(p) ((__attribute__((address_space(3))) unsigned int*)(p))
#define GLB_AS(p) ((const __attribute__((address_space(1))) unsigned int*)(p))

// ---------------------------------------------------------------------------
// Merged prep kernel (one launch, block-id partitioned):
//   blocks [0,512):    fold_w  W_eff^T[n][k] bf16, n-major (32k x 64n tiles)
//   block  512:        fold_b  b_eff fp32
//   blocks [513,4609): cvt     tokens fp32 -> bf16 (8 elems/thread)
// All HBM-bound; combined ~94 MB => ~15 us.
// ---------------------------------------------------------------------------
__global__ __launch_bounds__(256) void prep(const float* __restrict__ W,
                                            const float* __restrict__ tokens,
                                            const float* __restrict__ b,
                                            unsigned short* __restrict__ Wt,
                                            float* __restrict__ beff,
                                            uint4* __restrict__ Ab,
                                            int do_cvt) {
    __shared__ float T[32 * 65];
    const int t = threadIdx.x;
    const int bid = blockIdx.x;

    if (bid < 512) {  // ---- fold_w
        const int n0 = (bid & 15) * 64;
        const int k0 = (bid >> 4) * 32;
#pragma unroll
        for (int s = 0; s < 2; ++s) {
            int slot = s * 256 + t;
            int r = slot >> 4;              // k-local 0..31
            int c4 = (slot & 15) * 4;       // n-local float4
            const float4* src = (const float4*)(W + (size_t)(k0 + r) * 10240 + n0 + c4);
            float4 acc = {0.f, 0.f, 0.f, 0.f};
#pragma unroll
            for (int j = 0; j < 10; ++j) {
                float4 v = src[j * 256];
                acc.x += FW[j] * v.x; acc.y += FW[j] * v.y;
                acc.z += FW[j] * v.z; acc.w += FW[j] * v.w;
            }
            T[r * 65 + c4 + 0] = acc.x;
            T[r * 65 + c4 + 1] = acc.y;
            T[r * 65 + c4 + 2] = acc.z;
            T[r * 65 + c4 + 3] = acc.w;
        }
        __syncthreads();
#pragma unroll
        for (int s = 0; s < 2; ++s) {
            int slot = s * 256 + t;
            int nl = slot >> 3;             // n-local 0..63
            int k4 = (slot & 7) * 4;        // k-local group of 4
            float f0 = T[(k4 + 0) * 65 + nl];
            float f1 = T[(k4 + 1) * 65 + nl];
            float f2 = T[(k4 + 2) * 65 + nl];
            float f3 = T[(k4 + 3) * 65 + nl];
            uint2 p;
            p.x = bf16pack2(f1, f0);
            p.y = bf16pack2(f3, f2);
            *(uint2*)(Wt + (size_t)(n0 + nl) * 1024 + k0 + k4) = p;
        }
        return;
    }
    if (bid == 512) {  // ---- fold_b
        const float4* src = (const float4*)b + t;
        float4 acc = {0.f, 0.f, 0.f, 0.f};
#pragma unroll
        for (int j = 0; j < 10; ++j) {
            float4 v = src[j * 256];
            acc.x += FW[j] * v.x; acc.y += FW[j] * v.y;
            acc.z += FW[j] * v.z; acc.w += FW[j] * v.w;
        }
        ((float4*)beff)[t] = acc;
        return;
    }
    if (do_cvt) {  // ---- cvt tokens -> bf16 (row-major [8192][1024] bf16)
        size_t i = (size_t)(bid - 513) * 256 + t;
        const float4* src = (const float4*)tokens + i * 2;
        float4 a0 = src[0], a1 = src[1];
        uint4 p;
        p.x = bf16pack2(a0.y, a0.x);
        p.y = bf16pack2(a0.w, a0.z);
        p.z = bf16pack2(a1.y, a1.x);
        p.w = bf16pack2(a1.w, a1.z);
        Ab[i] = p;
    }
}

// ---------------------------------------------------------------------------
// GEMM: C[8192][1024] = Ab(bf16) @ Weff^T + b_eff
// 128x128 tile, 4 waves 2x2, each wave 64x64 = 2x2 of mfma_f32_32x32x16_bf16.
// BK=32, 32 K-steps, 4-slot LDS ring per operand (8KB/slot, 64KB total =>
// 2 blocks/CU). 2-deep prefetch with COUNTED vmcnt:
//   iter kt: s_waitcnt vmcnt(8)   (own tile-kt ops done; kt+1,kt+2 in flight)
//            s_barrier             (all waves' tile-kt ops done)
//            issue tile kt+3 (4 gll ops/wave)  -> outstanding back to 12
//            compute tile kt (8 ds_read_b128 + 8 MFMA / wave)
// Ring-4 holds exactly {reading kt, in-flight kt+1, kt+2, writing kt+3};
// buf[(kt+3)&3] held tile kt-1, whose reads all completed before barrier kt.
// LDS layout per 128x32-bf16 tile: row-pair interleave + XOR swizzle:
//   pair=m>>1, q=2c+(m&1), slot = pair*8 + (q ^ (pair&7))   (16B slots)
// -> conflict-free ds_read_b128 (8 consecutive pairs cover all 32 banks) and
// linear gll dest with pre-swizzled global source (both-sides rule, m173).
// Grid (64,8), x = M-tile: id%8 = M-tile%8 pins A stripes per XCD.
// ---------------------------------------------------------------------------
__global__ __launch_bounds__(256) void gemm32(const unsigned short* __restrict__ Ab,
                                              const unsigned short* __restrict__ Wt,
                                              const float* __restrict__ beff,
                                              float* __restrict__ C) {
    __shared__ __align__(16) unsigned char As[4][8192];
    __shared__ __align__(16) unsigned char Bs[4][8192];

    const int t = threadIdx.x;
    const int lane = t & 63;
    const int w = t >> 6;
    const int l31 = lane & 31;
    const int khalf = lane >> 5;       // 0/1: k-offset 0 or 8 within K=16
    const int wm = (w & 1) * 64;
    const int wn = (w >> 1) * 64;
    const int bm = blockIdx.x * 128;   // x fastest -> id%8 = M-tile%8 (XCD pin)
    const int bn = blockIdx.y * 128;

    floatx16 acc[2][2];
#pragma unroll
    for (int i = 0; i < 2; ++i)
#pragma unroll
        for (int j = 0; j < 2; ++j)
#pragma unroll
            for (int r = 0; r < 16; ++r) acc[i][j][r] = 0.f;

    const char* Abase = (const char*)Ab + (size_t)bm * 2048;  // bf16 rows
    const char* Bbase = (const char*)Wt + (size_t)bn * 2048;

    // staging: per tile per operand 512 slots x 16B = 8 gll ops; 2 ops/wave.
    // linear LDS slot s = I*64+lane -> logical (row, chunk) via inverse swizzle.
    int sm[2], sc[2];
#pragma unroll
    for (int i = 0; i < 2; ++i) {
        int s = (w * 2 + i) * 64 + lane;
        int pair = s >> 3;
        int q = (s & 7) ^ (pair & 7);
        sm[i] = pair * 2 + (q & 1);
        sc[i] = q >> 1;                 // 0..3 (16B chunk within 64B row-window)
    }

#define STAGE(KT)                                                                     \
    {                                                                                 \
        const size_t koff = (size_t)(KT) * 64;                                        \
        unsigned char* Ad = As[(KT) & 3];                                             \
        unsigned char* Bd = Bs[(KT) & 3];                                             \
        _Pragma("unroll") for (int i = 0; i < 2; ++i) {                               \
            int I = w * 2 + i;                                                        \
            __builtin_amdgcn_global_load_lds(                                         \
                GLB_AS(Abase + (size_t)sm[i] * 2048 + koff + sc[i] * 16),             \
                LDS_AS(Ad + I * 1024), 16, 0, 0);                                     \
            __builtin_amdgcn_global_load_lds(                                         \
                GLB_AS(Bbase + (size_t)sm[i] * 2048 + koff + sc[i] * 16),             \
                LDS_AS(Bd + I * 1024), 16, 0, 0);                                     \
        }                                                                             \
    }

    // ---- prologue: stage tiles 0,1,2 (12 ops/wave in tile order)
    STAGE(0)
    STAGE(1)
    STAGE(2)

#pragma unroll
    for (int kt = 0; kt < 32; ++kt) {
        // counted wait: own tile-kt ops (oldest 4) done; 8 newer stay in flight
        if (kt < 30)
            asm volatile("s_waitcnt vmcnt(8)" ::: "memory");
        else if (kt == 30)
            asm volatile("s_waitcnt vmcnt(4)" ::: "memory");
        else
            asm volatile("s_waitcnt vmcnt(0)" ::: "memory");
        __builtin_amdgcn_s_barrier();          // all waves' tile-kt staged
        __builtin_amdgcn_sched_barrier(0);     // ds_reads must not hoist above

        if (kt < 29) STAGE(kt + 3)             // overwrite buf of tile kt-1
        __builtin_amdgcn_sched_barrier(0);

        const unsigned char* Acur = As[kt & 3];
        const unsigned char* Bcur = Bs[kt & 3];
#pragma unroll
        for (int kk = 0; kk < 2; ++kk) {
            int f = kk * 2 + khalf;            // chunk 0..3 within 64B row
            short8 af[2], bf[2];
#pragma unroll
            for (int tm = 0; tm < 2; ++tm) {
                int m = wm + tm * 32 + l31;
                int slot = (m >> 1) * 8 + ((2 * f + (m & 1)) ^ ((m >> 1) & 7));
                af[tm] = *(const short8*)(Acur + slot * 16);
            }
#pragma unroll
            for (int tn = 0; tn < 2; ++tn) {
                int n = wn + tn * 32 + l31;
                int slot = (n >> 1) * 8 + ((2 * f + (n & 1)) ^ ((n >> 1) & 7));
                bf[tn] = *(const short8*)(Bcur + slot * 16);
            }
#pragma unroll
            for (int tm = 0; tm < 2; ++tm)
#pragma unroll
                for (int tn = 0; tn < 2; ++tn)
                    acc[tm][tn] = __builtin_amdgcn_mfma_f32_32x32x16_bf16(
                        af[tm], bf[tn], acc[tm][tn], 0, 0, 0);
        }
        __builtin_amdgcn_sched_barrier(0);     // keep iterations separated
    }
#undef STAGE

    // epilogue: col = lane&31, row = (reg&3) + 8*(reg>>2) + 4*(lane>>5)
#pragma unroll
    for (int tn = 0; tn < 2; ++tn) {
        int col = bn + wn + tn * 32 + l31;
        float bias = beff[col];
#pragma unroll
        for (int tm = 0; tm < 2; ++tm) {
            int rbase = bm + wm + tm * 32 + 4 * khalf;
#pragma unroll
            for (int r = 0; r < 16; ++r) {
                int row = rbase + (r & 3) + 8 * (r >> 2);
                C[(size_t)row * 1024 + col] = acc[tm][tn][r] + bias;
            }
        }
    }
}

// ---------------------------------------------------------------------------
// Fallback GEMM (fp32 A converted in-kernel) for small ws_size.
// ---------------------------------------------------------------------------
__global__ __launch_bounds__(256) void gemm_fb(const float* __restrict__ A,
                                               const unsigned short* __restrict__ Wt,
                                               const float* __restrict__ beff,
                                               float* __restrict__ C) {
    __shared__ __align__(16) unsigned short Asl[128 * 72];
    __shared__ __align__(16) unsigned char Bsl[16384];

    const int t = threadIdx.x;
    const int lane = t & 63;
    const int w = t >> 6;
    const int quad = lane >> 4;
    const int l15 = lane & 15;
    const int wm = (w & 1) * 64;
    const int wn = (w >> 1) * 64;
    const int bm = blockIdx.y * 128;
    const int bn = blockIdx.x * 128;

    floatx4 acc[4][4];
#pragma unroll
    for (int i = 0; i < 4; ++i)
#pragma unroll
        for (int j = 0; j < 4; ++j) acc[i][j] = (floatx4){0.f, 0.f, 0.f, 0.f};

    const int ar = t >> 4;
    const int ac4 = (t & 15) * 4;
    const float* Abase = A + (size_t)(bm + ar) * 1024 + ac4;
    const char* WtB = (const char*)Wt;

    for (int k0 = 0; k0 < 1024; k0 += 64) {
#pragma unroll
        for (int i = 0; i < 4; ++i) {
            int I = w * 4 + i;
            int slot = I * 64 + lane;
            int nl = slot >> 3;
            int c = (slot & 7) ^ (nl & 7);
            const char* g = WtB + (size_t)(bn + nl) * 2048 + k0 * 2 + c * 16;
            __builtin_amdgcn_global_load_lds(GLB_AS(g), LDS_AS(Bsl + I * 1024), 16, 0, 0);
        }
        float4 av[8];
#pragma unroll
        for (int s = 0; s < 8; ++s)
            av[s] = *(const float4*)(Abase + (size_t)(s * 16) * 1024 + k0);
#pragma unroll
        for (int s = 0; s < 8; ++s) {
            uint2 p;
            p.x = bf16pack2(av[s].y, av[s].x);
            p.y = bf16pack2(av[s].w, av[s].z);
            *(uint2*)((char*)Asl + (size_t)(s * 16 + ar) * 144 + ac4 * 2) = p;
        }
        __syncthreads();
#pragma unroll
        for (int kk = 0; kk < 2; ++kk) {
            short8 af[4], bf[4];
#pragma unroll
            for (int tm = 0; tm < 4; ++tm) {
                int m = wm + tm * 16 + l15;
                af[tm] = *(const short8*)((const char*)Asl + (size_t)m * 144 + kk * 64 + quad * 16);
            }
#pragma unroll
            for (int tn = 0; tn < 4; ++tn) {
                int n = wn + tn * 16 + l15;
                int c = kk * 4 + quad;
                int slot = n * 8 + (c ^ (n & 7));
                bf[tn] = *(const short8*)(Bsl + slot * 16);
            }
#pragma unroll
            for (int tm = 0; tm < 4; ++tm)
#pragma unroll
                for (int tn = 0; tn < 4; ++tn)
                    acc[tm][tn] = __builtin_amdgcn_mfma_f32_16x16x32_bf16(
                        af[tm], bf[tn], acc[tm][tn], 0, 0, 0);
        }
        __syncthreads();
    }
#pragma unroll
    for (int tn = 0; tn < 4; ++tn) {
        int col = bn + wn + tn * 16 + l15;
        float bias = beff[col];
#pragma unroll
        for (int tm = 0; tm < 4; ++tm) {
            int row0 = bm + wm + tm * 16 + quad * 4;
#pragma unroll
            for (int r = 0; r < 4; ++r)
                C[(size_t)(row0 + r) * 1024 + col] = acc[tm][tn][r] + bias;
        }
    }
}

extern "C" void kernel_launch(void* const* d_in, const int* in_sizes, int n_in,
                              void* d_out, int out_size, void* d_ws, size_t ws_size,
                              hipStream_t stream) {
    const float* tokens = (const float*)d_in[0];  // (4,2048,1024) fp32
    const float* W      = (const float*)d_in[1];  // (1024, 10240) fp32
    const float* b      = (const float*)d_in[2];  // (10240,) fp32
    float* out = (float*)d_out;                   // (4,2048,1024) fp32

    unsigned short* Wt = (unsigned short*)d_ws;                       // 2 MB bf16
    float* beff = (float*)((char*)d_ws + 2097152);                    // 4 KB fp32
    unsigned short* Ab = (unsigned short*)((char*)d_ws + 2101248);    // 16.8 MB bf16

    const int big_ws = ws_size >= 2101248 + (size_t)8192 * 1024 * 2;

    if (big_ws) {
        prep<<<513 + 4096, 256, 0, stream>>>(W, tokens, b, Wt, beff, (uint4*)Ab, 1);
        gemm32<<<dim3(64, 8), 256, 0, stream>>>(Ab, Wt, beff, out);
    } else {
        prep<<<513, 256, 0, stream>>>(W, tokens, b, Wt, beff, (uint4*)Ab, 0);
        gemm_fb<<<dim3(8, 64), 256, 0, stream>>>(tokens, Wt, beff, out);
    }
}

// Round 4
// 131.511 us; speedup vs baseline: 1.0131x; 1.0131x over previous
//
#include <hip/hip_runtime.h>
#include <stdint.h>

// out = tokens @ W_eff + b_eff, where W_eff folds the BULK_DIM=10 depth
// dimension with closed-form weights w_k = (1/10) * sum_{z=k..10} 1/z.
//
// v5: v4's ring-4 counted-vmcnt schedule kept verbatim, geometry changed to
// 512-thread blocks (8 waves of 32x64 output, same 128x128 tile, BK=32).
// Rationale: grid is fixed at 512 blocks / 2 per CU; with 256-thr blocks that
// was 8 waves/CU (2/SIMD) -- not enough TLP to hide barrier + LDS/L2 latency
// (v4 gemm ~40us ~ 430TF, plateaued vs round-0). 512-thr doubles resident
// waves to 16/CU (4/SIMD). vmcnt re-derived: 2 gll ops/tile/wave ->
// steady s_waitcnt vmcnt(4), tail 2 -> 0.

static constexpr float FW[10] = {
    0.2928968253968254f, 0.1928968253968254f, 0.1428968253968254f,
    0.1095634920634921f, 0.0845634920634921f, 0.0645634920634921f,
    0.0478968253968254f, 0.0336111111111111f, 0.0211111111111111f,
    0.0100000000000000f};

typedef __attribute__((ext_vector_type(8))) short short8;     // 8 bf16 = 4 VGPR
typedef __attribute__((ext_vector_type(4))) float floatx4;    // 16x16 C/D frag
typedef __attribute__((ext_vector_type(16))) float floatx16;  // 32x32 C/D frag

// round-to-nearest fp32->bf16, pack two into one uint via v_perm_b32
__device__ inline unsigned int bf16pack2(float hi, float lo) {
    unsigned int uh = __float_as_uint(hi) + 0x8000u;
    unsigned int ul = __float_as_uint(lo) + 0x8000u;
    return __builtin_amdgcn_perm(uh, ul, 0x07060302u);  // {hi[31:16], lo[31:16]}
}

#define LDS_AS(p) ((__attribute__((address_space(3))) unsigned int*)(p))
#define GLB_AS(p) ((const __attribute__((address_space(1))) unsigned int*)(p))

// ---------------------------------------------------------------------------
// Merged prep kernel (one launch, block-id partitioned):
//   blocks [0,512):    fold_w  W_eff^T[n][k] bf16, n-major (32k x 64n tiles)
//   block  512:        fold_b  b_eff fp32
//   blocks [513,4609): cvt     tokens fp32 -> bf16 (8 elems/thread)
// All HBM-bound; combined ~94 MB.
// ---------------------------------------------------------------------------
__global__ __launch_bounds__(256) void prep(const float* __restrict__ W,
                                            const float* __restrict__ tokens,
                                            const float* __restrict__ b,
                                            unsigned short* __restrict__ Wt,
                                            float* __restrict__ beff,
                                            uint4* __restrict__ Ab,
                                            int do_cvt) {
    __shared__ float T[32 * 65];
    const int t = threadIdx.x;
    const int bid = blockIdx.x;

    if (bid < 512) {  // ---- fold_w
        const int n0 = (bid & 15) * 64;
        const int k0 = (bid >> 4) * 32;
#pragma unroll
        for (int s = 0; s < 2; ++s) {
            int slot = s * 256 + t;
            int r = slot >> 4;              // k-local 0..31
            int c4 = (slot & 15) * 4;       // n-local float4
            const float4* src = (const float4*)(W + (size_t)(k0 + r) * 10240 + n0 + c4);
            float4 acc = {0.f, 0.f, 0.f, 0.f};
#pragma unroll
            for (int j = 0; j < 10; ++j) {
                float4 v = src[j * 256];
                acc.x += FW[j] * v.x; acc.y += FW[j] * v.y;
                acc.z += FW[j] * v.z; acc.w += FW[j] * v.w;
            }
            T[r * 65 + c4 + 0] = acc.x;
            T[r * 65 + c4 + 1] = acc.y;
            T[r * 65 + c4 + 2] = acc.z;
            T[r * 65 + c4 + 3] = acc.w;
        }
        __syncthreads();
#pragma unroll
        for (int s = 0; s < 2; ++s) {
            int slot = s * 256 + t;
            int nl = slot >> 3;             // n-local 0..63
            int k4 = (slot & 7) * 4;        // k-local group of 4
            float f0 = T[(k4 + 0) * 65 + nl];
            float f1 = T[(k4 + 1) * 65 + nl];
            float f2 = T[(k4 + 2) * 65 + nl];
            float f3 = T[(k4 + 3) * 65 + nl];
            uint2 p;
            p.x = bf16pack2(f1, f0);
            p.y = bf16pack2(f3, f2);
            *(uint2*)(Wt + (size_t)(n0 + nl) * 1024 + k0 + k4) = p;
        }
        return;
    }
    if (bid == 512) {  // ---- fold_b
        const float4* src = (const float4*)b + t;
        float4 acc = {0.f, 0.f, 0.f, 0.f};
#pragma unroll
        for (int j = 0; j < 10; ++j) {
            float4 v = src[j * 256];
            acc.x += FW[j] * v.x; acc.y += FW[j] * v.y;
            acc.z += FW[j] * v.z; acc.w += FW[j] * v.w;
        }
        ((float4*)beff)[t] = acc;
        return;
    }
    if (do_cvt) {  // ---- cvt tokens -> bf16 (row-major [8192][1024] bf16)
        size_t i = (size_t)(bid - 513) * 256 + t;
        const float4* src = (const float4*)tokens + i * 2;
        float4 a0 = src[0], a1 = src[1];
        uint4 p;
        p.x = bf16pack2(a0.y, a0.x);
        p.y = bf16pack2(a0.w, a0.z);
        p.z = bf16pack2(a1.y, a1.x);
        p.w = bf16pack2(a1.w, a1.z);
        Ab[i] = p;
    }
}

// ---------------------------------------------------------------------------
// GEMM: C[8192][1024] = Ab(bf16) @ Weff^T + b_eff
// 128x128 tile, 512 threads, 8 waves each 32(M)x64(N) = 1x2 of 32x32x16 MFMA.
// BK=32, 32 K-steps, 4-slot LDS ring per operand (8KB/slot, 64KB total =>
// 2 blocks/CU = 16 waves/CU = 4 waves/SIMD). 2-deep prefetch, COUNTED vmcnt:
//   iter kt: s_waitcnt vmcnt(4)   (own tile-kt ops done; kt+1,kt+2 in flight)
//            s_barrier             (all waves' tile-kt ops done)
//            issue tile kt+3 (2 gll ops/wave)  -> outstanding back to 6
//            compute tile kt (6 ds_read_b128 + 4 MFMA / wave)
// Ring-4 holds exactly {reading kt, in-flight kt+1, kt+2, writing kt+3};
// buf[(kt+3)&3] held tile kt-1, whose reads all completed before barrier kt.
// LDS layout per 128x32-bf16 tile: row-pair interleave + XOR swizzle:
//   pair=m>>1, q=2c+(m&1), slot = pair*8 + (q ^ (pair&7))   (16B slots)
// staged with linear gll dest (base + lane*16) + pre-swizzled global source.
// Grid (64,8), x = M-tile: id%8 = M-tile%8 pins A stripes per XCD.
// ---------------------------------------------------------------------------
__global__ __launch_bounds__(512) void gemm32(const unsigned short* __restrict__ Ab,
                                              const unsigned short* __restrict__ Wt,
                                              const float* __restrict__ beff,
                                              float* __restrict__ C) {
    __shared__ __align__(16) unsigned char As[4][8192];
    __shared__ __align__(16) unsigned char Bs[4][8192];

    const int t = threadIdx.x;
    const int lane = t & 63;
    const int w = t >> 6;              // 0..7
    const int l31 = lane & 31;
    const int khalf = lane >> 5;       // 0/1: k-offset 0 or 8 within K=16
    const int wm = (w & 3) * 32;       // 4 M-positions
    const int wn = (w >> 2) * 64;      // 2 N-positions
    const int bm = blockIdx.x * 128;   // x fastest -> id%8 = M-tile%8 (XCD pin)
    const int bn = blockIdx.y * 128;

    floatx16 acc[2];
#pragma unroll
    for (int j = 0; j < 2; ++j)
#pragma unroll
        for (int r = 0; r < 16; ++r) acc[j][r] = 0.f;

    const char* Abase = (const char*)Ab + (size_t)bm * 2048;  // bf16 rows
    const char* Bbase = (const char*)Wt + (size_t)bn * 2048;

    // staging: per tile per operand 512 slots x 16B; thread t stages slot t
    // (1 gll op per operand per wave). Inverse swizzle for the global source.
    const int pair = t >> 3;
    const int q = (t & 7) ^ (pair & 7);
    const int sm = pair * 2 + (q & 1);      // logical row 0..127
    const int sc = q >> 1;                  // 16B chunk 0..3 within 64B window

#define STAGE(KT)                                                                     \
    {                                                                                 \
        const size_t koff = (size_t)(KT) * 64;                                        \
        unsigned char* Ad = As[(KT) & 3];                                             \
        unsigned char* Bd = Bs[(KT) & 3];                                             \
        __builtin_amdgcn_global_load_lds(                                             \
            GLB_AS(Abase + (size_t)sm * 2048 + koff + sc * 16),                       \
            LDS_AS(Ad + w * 1024), 16, 0, 0);                                         \
        __builtin_amdgcn_global_load_lds(                                             \
            GLB_AS(Bbase + (size_t)sm * 2048 + koff + sc * 16),                       \
            LDS_AS(Bd + w * 1024), 16, 0, 0);                                         \
    }

    // ---- prologue: stage tiles 0,1,2 (6 ops/wave in tile order)
    STAGE(0)
    STAGE(1)
    STAGE(2)

#pragma unroll
    for (int kt = 0; kt < 32; ++kt) {
        // counted wait: own tile-kt ops (oldest 2) done; newer stay in flight
        if (kt < 30)
            asm volatile("s_waitcnt vmcnt(4)" ::: "memory");
        else if (kt == 30)
            asm volatile("s_waitcnt vmcnt(2)" ::: "memory");
        else
            asm volatile("s_waitcnt vmcnt(0)" ::: "memory");
        __builtin_amdgcn_s_barrier();          // all waves' tile-kt staged
        __builtin_amdgcn_sched_barrier(0);     // ds_reads must not hoist above

        if (kt < 29) STAGE(kt + 3)             // overwrite buf of tile kt-1
        __builtin_amdgcn_sched_barrier(0);

        const unsigned char* Acur = As[kt & 3];
        const unsigned char* Bcur = Bs[kt & 3];
#pragma unroll
        for (int kk = 0; kk < 2; ++kk) {
            int f = kk * 2 + khalf;            // chunk 0..3 within 64B row
            short8 af, bf[2];
            {
                int m = wm + l31;
                int slot = (m >> 1) * 8 + ((2 * f + (m & 1)) ^ ((m >> 1) & 7));
                af = *(const short8*)(Acur + slot * 16);
            }
#pragma unroll
            for (int tn = 0; tn < 2; ++tn) {
                int n = wn + tn * 32 + l31;
                int slot = (n >> 1) * 8 + ((2 * f + (n & 1)) ^ ((n >> 1) & 7));
                bf[tn] = *(const short8*)(Bcur + slot * 16);
            }
#pragma unroll
            for (int tn = 0; tn < 2; ++tn)
                acc[tn] = __builtin_amdgcn_mfma_f32_32x32x16_bf16(
                    af, bf[tn], acc[tn], 0, 0, 0);
        }
        __builtin_amdgcn_sched_barrier(0);     // keep iterations separated
    }
#undef STAGE

    // epilogue: col = lane&31, row = (reg&3) + 8*(reg>>2) + 4*(lane>>5)
#pragma unroll
    for (int tn = 0; tn < 2; ++tn) {
        int col = bn + wn + tn * 32 + l31;
        float bias = beff[col];
        int rbase = bm + wm + 4 * khalf;
#pragma unroll
        for (int r = 0; r < 16; ++r) {
            int row = rbase + (r & 3) + 8 * (r >> 2);
            C[(size_t)row * 1024 + col] = acc[tn][r] + bias;
        }
    }
}

// ---------------------------------------------------------------------------
// Fallback GEMM (fp32 A converted in-kernel) for small ws_size.
// ---------------------------------------------------------------------------
__global__ __launch_bounds__(256) void gemm_fb(const float* __restrict__ A,
                                               const unsigned short* __restrict__ Wt,
                                               const float* __restrict__ beff,
                                               float* __restrict__ C) {
    __shared__ __align__(16) unsigned short Asl[128 * 72];
    __shared__ __align__(16) unsigned char Bsl[16384];

    const int t = threadIdx.x;
    const int lane = t & 63;
    const int w = t >> 6;
    const int quad = lane >> 4;
    const int l15 = lane & 15;
    const int wm = (w & 1) * 64;
    const int wn = (w >> 1) * 64;
    const int bm = blockIdx.y * 128;
    const int bn = blockIdx.x * 128;

    floatx4 acc[4][4];
#pragma unroll
    for (int i = 0; i < 4; ++i)
#pragma unroll
        for (int j = 0; j < 4; ++j) acc[i][j] = (floatx4){0.f, 0.f, 0.f, 0.f};

    const int ar = t >> 4;
    const int ac4 = (t & 15) * 4;
    const float* Abase = A + (size_t)(bm + ar) * 1024 + ac4;
    const char* WtB = (const char*)Wt;

    for (int k0 = 0; k0 < 1024; k0 += 64) {
#pragma unroll
        for (int i = 0; i < 4; ++i) {
            int I = w * 4 + i;
            int slot = I * 64 + lane;
            int nl = slot >> 3;
            int c = (slot & 7) ^ (nl & 7);
            const char* g = WtB + (size_t)(bn + nl) * 2048 + k0 * 2 + c * 16;
            __builtin_amdgcn_global_load_lds(GLB_AS(g), LDS_AS(Bsl + I * 1024), 16, 0, 0);
        }
        float4 av[8];
#pragma unroll
        for (int s = 0; s < 8; ++s)
            av[s] = *(const float4*)(Abase + (size_t)(s * 16) * 1024 + k0);
#pragma unroll
        for (int s = 0; s < 8; ++s) {
            uint2 p;
            p.x = bf16pack2(av[s].y, av[s].x);
            p.y = bf16pack2(av[s].w, av[s].z);
            *(uint2*)((char*)Asl + (size_t)(s * 16 + ar) * 144 + ac4 * 2) = p;
        }
        __syncthreads();
#pragma unroll
        for (int kk = 0; kk < 2; ++kk) {
            short8 af[4], bf[4];
#pragma unroll
            for (int tm = 0; tm < 4; ++tm) {
                int m = wm + tm * 16 + l15;
                af[tm] = *(const short8*)((const char*)Asl + (size_t)m * 144 + kk * 64 + quad * 16);
            }
#pragma unroll
            for (int tn = 0; tn < 4; ++tn) {
                int n = wn + tn * 16 + l15;
                int c = kk * 4 + quad;
                int slot = n * 8 + (c ^ (n & 7));
                bf[tn] = *(const short8*)(Bsl + slot * 16);
            }
#pragma unroll
            for (int tm = 0; tm < 4; ++tm)
#pragma unroll
                for (int tn = 0; tn < 4; ++tn)
                    acc[tm][tn] = __builtin_amdgcn_mfma_f32_16x16x32_bf16(
                        af[tm], bf[tn], acc[tm][tn], 0, 0, 0);
        }
        __syncthreads();
    }
#pragma unroll
    for (int tn = 0; tn < 4; ++tn) {
        int col = bn + wn + tn * 16 + l15;
        float bias = beff[col];
#pragma unroll
        for (int tm = 0; tm < 4; ++tm) {
            int row0 = bm + wm + tm * 16 + quad * 4;
#pragma unroll
            for (int r = 0; r < 4; ++r)
                C[(size_t)(row0 + r) * 1024 + col] = acc[tm][tn][r] + bias;
        }
    }
}

extern "C" void kernel_launch(void* const* d_in, const int* in_sizes, int n_in,
                              void* d_out, int out_size, void* d_ws, size_t ws_size,
                              hipStream_t stream) {
    const float* tokens = (const float*)d_in[0];  // (4,2048,1024) fp32
    const float* W      = (const float*)d_in[1];  // (1024, 10240) fp32
    const float* b      = (const float*)d_in[2];  // (10240,) fp32
    float* out = (float*)d_out;                   // (4,2048,1024) fp32

    unsigned short* Wt = (unsigned short*)d_ws;                       // 2 MB bf16
    float* beff = (float*)((char*)d_ws + 2097152);                    // 4 KB fp32
    unsigned short* Ab = (unsigned short*)((char*)d_ws + 2101248);    // 16.8 MB bf16

    const int big_ws = ws_size >= 2101248 + (size_t)8192 * 1024 * 2;

    if (big_ws) {
        prep<<<513 + 4096, 256, 0, stream>>>(W, tokens, b, Wt, beff, (uint4*)Ab, 1);
        gemm32<<<dim3(64, 8), 512, 0, stream>>>(Ab, Wt, beff, out);
    } else {
        prep<<<513, 256, 0, stream>>>(W, tokens, b, Wt, beff, (uint4*)Ab, 0);
        gemm_fb<<<dim3(8, 64), 256, 0, stream>>>(tokens, Wt, beff, out);
    }
}

// Round 5
// 129.440 us; speedup vs baseline: 1.0293x; 1.0160x over previous
//
#include <hip/hip_runtime.h>
#include <stdint.h>

// out = tokens @ W_eff + b_eff, where W_eff folds the BULK_DIM=10 depth
// dimension with closed-form weights w_k = (1/10) * sum_{z=k..10} 1/z.
// (The reference scan is the running mean; averaging over depth gives these.)
//
// FINAL (restored round-0 best, 129.9us this session / 129.2us prior session).
// Session findings that justify this structure:
//  - metric floor is harness-dominated (268MB re-poison fill @41us + fixed
//    ~90us); kernel-time deltas of 20-40us move dur_us by <= noise (+-4us).
//  - two-pass traffic (~142MB ~= 24us) is within 7.5us of the 104MB
//    single-pass floor; fusion is blocked by compiler IR load-sinking
//    (v2/v3: VGPR=88, A loads serialized, gemm 58us).
//  - ring-4 counted-vmcnt and 512-thr variants (v4/v5): no measurable gain.

static constexpr float FW[10] = {
    0.2928968253968254f, 0.1928968253968254f, 0.1428968253968254f,
    0.1095634920634921f, 0.0845634920634921f, 0.0645634920634921f,
    0.0478968253968254f, 0.0336111111111111f, 0.0211111111111111f,
    0.0100000000000000f};

typedef __attribute__((ext_vector_type(8))) short short8;     // 8 bf16 = 4 VGPR
typedef __attribute__((ext_vector_type(4))) float floatx4;    // 16x16 C/D frag
typedef __attribute__((ext_vector_type(16))) float floatx16;  // 32x32 C/D frag

// round-to-nearest fp32->bf16, pack two into one uint via v_perm_b32
__device__ inline unsigned int bf16pack2(float hi, float lo) {
    unsigned int uh = __float_as_uint(hi) + 0x8000u;
    unsigned int ul = __float_as_uint(lo) + 0x8000u;
    return __builtin_amdgcn_perm(uh, ul, 0x07060302u);  // {hi[31:16], lo[31:16]}
}

#define LDS_AS(p) ((__attribute__((address_space(3))) unsigned int*)(p))
#define GLB_AS(p) ((const __attribute__((address_space(1))) unsigned int*)(p))

// ---------------------------------------------------------------------------
// Merged prep kernel (one launch, block-id partitioned):
//   blocks [0,512):    fold_w  W_eff^T[n][k] bf16, n-major (32k x 64n tiles)
//   block  512:        fold_b  b_eff fp32
//   blocks [513,4609): cvt     tokens fp32 -> bf16 (8 elems/thread)
// All HBM-bound; combined ~94 MB => ~15-16 us.
// ---------------------------------------------------------------------------
__global__ __launch_bounds__(256) void prep(const float* __restrict__ W,
                                            const float* __restrict__ tokens,
                                            const float* __restrict__ b,
                                            unsigned short* __restrict__ Wt,
                                            float* __restrict__ beff,
                                            uint4* __restrict__ Ab,
                                            int do_cvt) {
    __shared__ float T[32 * 65];
    const int t = threadIdx.x;
    const int bid = blockIdx.x;

    if (bid < 512) {  // ---- fold_w
        const int n0 = (bid & 15) * 64;
        const int k0 = (bid >> 4) * 32;
#pragma unroll
        for (int s = 0; s < 2; ++s) {
            int slot = s * 256 + t;
            int r = slot >> 4;              // k-local 0..31
            int c4 = (slot & 15) * 4;       // n-local float4
            const float4* src = (const float4*)(W + (size_t)(k0 + r) * 10240 + n0 + c4);
            float4 acc = {0.f, 0.f, 0.f, 0.f};
#pragma unroll
            for (int j = 0; j < 10; ++j) {
                float4 v = src[j * 256];
                acc.x += FW[j] * v.x; acc.y += FW[j] * v.y;
                acc.z += FW[j] * v.z; acc.w += FW[j] * v.w;
            }
            T[r * 65 + c4 + 0] = acc.x;
            T[r * 65 + c4 + 1] = acc.y;
            T[r * 65 + c4 + 2] = acc.z;
            T[r * 65 + c4 + 3] = acc.w;
        }
        __syncthreads();
#pragma unroll
        for (int s = 0; s < 2; ++s) {
            int slot = s * 256 + t;
            int nl = slot >> 3;             // n-local 0..63
            int k4 = (slot & 7) * 4;        // k-local group of 4
            float f0 = T[(k4 + 0) * 65 + nl];
            float f1 = T[(k4 + 1) * 65 + nl];
            float f2 = T[(k4 + 2) * 65 + nl];
            float f3 = T[(k4 + 3) * 65 + nl];
            uint2 p;
            p.x = bf16pack2(f1, f0);
            p.y = bf16pack2(f3, f2);
            *(uint2*)(Wt + (size_t)(n0 + nl) * 1024 + k0 + k4) = p;
        }
        return;
    }
    if (bid == 512) {  // ---- fold_b
        const float4* src = (const float4*)b + t;
        float4 acc = {0.f, 0.f, 0.f, 0.f};
#pragma unroll
        for (int j = 0; j < 10; ++j) {
            float4 v = src[j * 256];
            acc.x += FW[j] * v.x; acc.y += FW[j] * v.y;
            acc.z += FW[j] * v.z; acc.w += FW[j] * v.w;
        }
        ((float4*)beff)[t] = acc;
        return;
    }
    if (do_cvt) {  // ---- cvt tokens -> bf16
        size_t i = (size_t)(bid - 513) * 256 + t;
        const float4* src = (const float4*)tokens + i * 2;
        float4 a0 = src[0], a1 = src[1];
        uint4 p;
        p.x = bf16pack2(a0.y, a0.x);
        p.y = bf16pack2(a0.w, a0.z);
        p.z = bf16pack2(a1.y, a1.x);
        p.w = bf16pack2(a1.w, a1.z);
        Ab[i] = p;
    }
}

// ---------------------------------------------------------------------------
// GEMM: C[8192][1024] = Ab(bf16) @ Weff^T + b_eff
// 128x128 tile, 4 waves 2x2, each wave 64x64 = 2x2 of mfma_f32_32x32x16_bf16.
// BK=64, DOUBLE-BUFFERED LDS (2 x 16KB per operand = 64KB/block, 2 blocks/CU).
// Pipeline order per iter: barrier -> issue prefetch(tile k+1) -> compute(k).
// The compiler's vmcnt(0) drain before the NEXT barrier then waits on loads
// issued a full compute phase earlier -> drain hidden (vs m97 structure where
// loads are issued right before the barrier).
// XOR swizzle slot = row*8 + (chunk ^ (row&7)); frag ds_read_b128 2-way free.
// Grid (64,8), x = M-tile: id%8 = M-tile%8 pins A stripes per XCD.
// ---------------------------------------------------------------------------
__global__ __launch_bounds__(256) void gemm32(const unsigned short* __restrict__ Ab,
                                              const unsigned short* __restrict__ Wt,
                                              const float* __restrict__ beff,
                                              float* __restrict__ C) {
    __shared__ __align__(16) unsigned char As[2][16384];  // 128 rows x 8 chunks x 16B
    __shared__ __align__(16) unsigned char Bs[2][16384];

    const int t = threadIdx.x;
    const int lane = t & 63;
    const int w = t >> 6;
    const int l31 = lane & 31;
    const int khalf = lane >> 5;       // 0/1: k-offset 0 or 8 within K=16
    const int wm = (w & 1) * 64;
    const int wn = (w >> 1) * 64;
    const int bm = blockIdx.x * 128;   // x fastest -> id%8 = M-tile%8 (XCD pin)
    const int bn = blockIdx.y * 128;

    floatx16 acc[2][2];
#pragma unroll
    for (int i = 0; i < 2; ++i)
#pragma unroll
        for (int j = 0; j < 2; ++j)
#pragma unroll
            for (int r = 0; r < 16; ++r) acc[i][j][r] = 0.f;

    const char* Abase = (const char*)Ab + (size_t)bm * 2048;
    const char* Bbase = (const char*)Wt + (size_t)bn * 2048;

    // staging: 1024 slots of 16B per operand, 4 instr/wave each
    const int sI = w * 4;  // this wave's first LDS row-group

    // prologue: stage tile 0 into buffer 0
#pragma unroll
    for (int i = 0; i < 4; ++i) {
        int I = sI + i;
        int slot = I * 64 + lane;
        int m = slot >> 3;
        int c = (slot & 7) ^ (m & 7);
        size_t off = (size_t)m * 2048 + c * 16;
        __builtin_amdgcn_global_load_lds(GLB_AS(Abase + off), LDS_AS(As[0] + I * 1024), 16, 0, 0);
        __builtin_amdgcn_global_load_lds(GLB_AS(Bbase + off), LDS_AS(Bs[0] + I * 1024), 16, 0, 0);
    }

#pragma unroll
    for (int kt = 0; kt < 16; ++kt) {
        __syncthreads();  // tile kt staged (prefetched a full compute phase ago)

        if (kt < 15) {    // prefetch tile kt+1 into the other buffer
            int k0n = (kt + 1) * 64;
            int buf = (kt + 1) & 1;
#pragma unroll
            for (int i = 0; i < 4; ++i) {
                int I = sI + i;
                int slot = I * 64 + lane;
                int m = slot >> 3;
                int c = (slot & 7) ^ (m & 7);
                size_t off = (size_t)m * 2048 + (size_t)k0n * 2 + c * 16;
                __builtin_amdgcn_global_load_lds(GLB_AS(Abase + off), LDS_AS(As[buf] + I * 1024), 16, 0, 0);
                __builtin_amdgcn_global_load_lds(GLB_AS(Bbase + off), LDS_AS(Bs[buf] + I * 1024), 16, 0, 0);
            }
        }

        const unsigned char* Acur = As[kt & 1];
        const unsigned char* Bcur = Bs[kt & 1];
#pragma unroll
        for (int kk = 0; kk < 4; ++kk) {
            int c = kk * 2 + khalf;        // logical chunk 0..7
            short8 af[2], bf[2];
#pragma unroll
            for (int tm = 0; tm < 2; ++tm) {
                int m = wm + tm * 32 + l31;
                int slot = m * 8 + (c ^ (m & 7));
                af[tm] = *(const short8*)(Acur + slot * 16);
            }
#pragma unroll
            for (int tn = 0; tn < 2; ++tn) {
                int n = wn + tn * 32 + l31;
                int slot = n * 8 + (c ^ (n & 7));
                bf[tn] = *(const short8*)(Bcur + slot * 16);
            }
#pragma unroll
            for (int tm = 0; tm < 2; ++tm)
#pragma unroll
                for (int tn = 0; tn < 2; ++tn)
                    acc[tm][tn] = __builtin_amdgcn_mfma_f32_32x32x16_bf16(
                        af[tm], bf[tn], acc[tm][tn], 0, 0, 0);
        }
    }

    // epilogue: col = lane&31, row = (reg&3) + 8*(reg>>2) + 4*(lane>>5)
#pragma unroll
    for (int tn = 0; tn < 2; ++tn) {
        int col = bn + wn + tn * 32 + l31;
        float bias = beff[col];
#pragma unroll
        for (int tm = 0; tm < 2; ++tm) {
            int rbase = bm + wm + tm * 32 + 4 * khalf;
#pragma unroll
            for (int r = 0; r < 16; ++r) {
                int row = rbase + (r & 3) + 8 * (r >> 2);
                C[(size_t)row * 1024 + col] = acc[tm][tn][r] + bias;
            }
        }
    }
}

// ---------------------------------------------------------------------------
// Fallback GEMM (fp32 A converted in-kernel) for small ws_size.
// ---------------------------------------------------------------------------
__global__ __launch_bounds__(256) void gemm_fb(const float* __restrict__ A,
                                               const unsigned short* __restrict__ Wt,
                                               const float* __restrict__ beff,
                                               float* __restrict__ C) {
    __shared__ __align__(16) unsigned short As[128 * 72];
    __shared__ __align__(16) unsigned char Bs[16384];

    const int t = threadIdx.x;
    const int lane = t & 63;
    const int w = t >> 6;
    const int quad = lane >> 4;
    const int l15 = lane & 15;
    const int wm = (w & 1) * 64;
    const int wn = (w >> 1) * 64;
    const int bm = blockIdx.y * 128;
    const int bn = blockIdx.x * 128;

    floatx4 acc[4][4];
#pragma unroll
    for (int i = 0; i < 4; ++i)
#pragma unroll
        for (int j = 0; j < 4; ++j) acc[i][j] = (floatx4){0.f, 0.f, 0.f, 0.f};

    const int ar = t >> 4;
    const int ac4 = (t & 15) * 4;
    const float* Abase = A + (size_t)(bm + ar) * 1024 + ac4;
    const char* WtB = (const char*)Wt;

    for (int k0 = 0; k0 < 1024; k0 += 64) {
#pragma unroll
        for (int i = 0; i < 4; ++i) {
            int I = w * 4 + i;
            int slot = I * 64 + lane;
            int nl = slot >> 3;
            int c = (slot & 7) ^ (nl & 7);
            const char* g = WtB + (size_t)(bn + nl) * 2048 + k0 * 2 + c * 16;
            __builtin_amdgcn_global_load_lds(GLB_AS(g), LDS_AS(Bs + I * 1024), 16, 0, 0);
        }
        float4 av[8];
#pragma unroll
        for (int s = 0; s < 8; ++s)
            av[s] = *(const float4*)(Abase + (size_t)(s * 16) * 1024 + k0);
#pragma unroll
        for (int s = 0; s < 8; ++s) {
            uint2 p;
            p.x = bf16pack2(av[s].y, av[s].x);
            p.y = bf16pack2(av[s].w, av[s].z);
            *(uint2*)((char*)As + (size_t)(s * 16 + ar) * 144 + ac4 * 2) = p;
        }
        __syncthreads();
#pragma unroll
        for (int kk = 0; kk < 2; ++kk) {
            short8 af[4], bf[4];
#pragma unroll
            for (int tm = 0; tm < 4; ++tm) {
                int m = wm + tm * 16 + l15;
                af[tm] = *(const short8*)((const char*)As + (size_t)m * 144 + kk * 64 + quad * 16);
            }
#pragma unroll
            for (int tn = 0; tn < 4; ++tn) {
                int n = wn + tn * 16 + l15;
                int c = kk * 4 + quad;
                int slot = n * 8 + (c ^ (n & 7));
                bf[tn] = *(const short8*)(Bs + slot * 16);
            }
#pragma unroll
            for (int tm = 0; tm < 4; ++tm)
#pragma unroll
                for (int tn = 0; tn < 4; ++tn)
                    acc[tm][tn] = __builtin_amdgcn_mfma_f32_16x16x32_bf16(
                        af[tm], bf[tn], acc[tm][tn], 0, 0, 0);
        }
        __syncthreads();
    }
#pragma unroll
    for (int tn = 0; tn < 4; ++tn) {
        int col = bn + wn + tn * 16 + l15;
        float bias = beff[col];
#pragma unroll
        for (int tm = 0; tm < 4; ++tm) {
            int row0 = bm + wm + tm * 16 + quad * 4;
#pragma unroll
            for (int r = 0; r < 4; ++r)
                C[(size_t)(row0 + r) * 1024 + col] = acc[tm][tn][r] + bias;
        }
    }
}

extern "C" void kernel_launch(void* const* d_in, const int* in_sizes, int n_in,
                              void* d_out, int out_size, void* d_ws, size_t ws_size,
                              hipStream_t stream) {
    const float* tokens = (const float*)d_in[0];  // (4,2048,1024) fp32
    const float* W      = (const float*)d_in[1];  // (1024, 10240) fp32
    const float* b      = (const float*)d_in[2];  // (10240,) fp32
    float* out = (float*)d_out;                   // (4,2048,1024) fp32

    unsigned short* Wt = (unsigned short*)d_ws;                       // 2 MB bf16
    float* beff = (float*)((char*)d_ws + 2097152);                    // 4 KB fp32
    unsigned short* Ab = (unsigned short*)((char*)d_ws + 2101248);    // 16.8 MB bf16

    const int big_ws = ws_size >= 2101248 + (size_t)8192 * 1024 * 2;

    if (big_ws) {
        prep<<<513 + 4096, 256, 0, stream>>>(W, tokens, b, Wt, beff, (uint4*)Ab, 1);
        gemm32<<<dim3(64, 8), 256, 0, stream>>>(Ab, Wt, beff, out);
    } else {
        prep<<<513, 256, 0, stream>>>(W, tokens, b, Wt, beff, (uint4*)Ab, 0);
        gemm_fb<<<dim3(8, 64), 256, 0, stream>>>(tokens, Wt, beff, out);
    }
}